// Round 6
// baseline (484.485 us; speedup 1.0000x reference)
//
#include <hip/hip_runtime.h>
#include <math.h>

#define DQ 2048
#define CDIM 512
#define NKEYS 256
#define KSEL 32

__device__ __forceinline__ bool rank_before(float as, int ai, float bs, int bi) {
  return (as > bs) || (as == bs && ai < bi);
}
static __device__ __forceinline__ float bf2f(unsigned int u) {
  union { unsigned int i; float f; } v; v.i = u << 16; return v.f;
}
static __device__ __forceinline__ unsigned int f2bf(float f) {
  union { float f; unsigned int i; } v; v.f = f;
  unsigned int r = v.i + 0x7fffu + ((v.i >> 16) & 1u);
  return r >> 16;
}

// ---------------- q = LN(X * Wq^T): 128x128 tile, 8x8/thread ----------------
__global__ __launch_bounds__(256) void qgemm_ln(
    const float* __restrict__ X, const float* __restrict__ W,
    const float* __restrict__ gamma, const float* __restrict__ beta,
    float* __restrict__ Q) {
  __shared__ float As[32 * 132];  // [k][m]
  __shared__ float Bs[32 * 132];  // [k][n]
  const int tid = threadIdx.x;
  const int m0 = blockIdx.x * 128, n0 = blockIdx.y * 128;
  const int tx = tid & 15, ty = tid >> 4;
  const int sr = tid >> 1, sk = (tid & 1) * 16;  // staging: 128 rows x 32 k
  float4 pa[4], pb[4];
  #pragma unroll
  for (int q = 0; q < 4; ++q) {
    pa[q] = *(const float4*)&X[(size_t)(m0 + sr) * CDIM + sk + q * 4];
    pb[q] = *(const float4*)&W[(size_t)(n0 + sr) * CDIM + sk + q * 4];
  }
  float acc[8][8] = {};
  for (int kt = 0; kt < CDIM; kt += 32) {
    __syncthreads();
    #pragma unroll
    for (int q = 0; q < 4; ++q) {
      As[(sk + q * 4 + 0) * 132 + sr] = pa[q].x;
      As[(sk + q * 4 + 1) * 132 + sr] = pa[q].y;
      As[(sk + q * 4 + 2) * 132 + sr] = pa[q].z;
      As[(sk + q * 4 + 3) * 132 + sr] = pa[q].w;
      Bs[(sk + q * 4 + 0) * 132 + sr] = pb[q].x;
      Bs[(sk + q * 4 + 1) * 132 + sr] = pb[q].y;
      Bs[(sk + q * 4 + 2) * 132 + sr] = pb[q].z;
      Bs[(sk + q * 4 + 3) * 132 + sr] = pb[q].w;
    }
    __syncthreads();
    if (kt + 32 < CDIM) {
      #pragma unroll
      for (int q = 0; q < 4; ++q) {
        pa[q] = *(const float4*)&X[(size_t)(m0 + sr) * CDIM + kt + 32 + sk + q * 4];
        pb[q] = *(const float4*)&W[(size_t)(n0 + sr) * CDIM + kt + 32 + sk + q * 4];
      }
    }
    #pragma unroll 8
    for (int kk = 0; kk < 32; ++kk) {
      float a[8], b[8];
      *(float4*)&a[0] = *(const float4*)&As[kk * 132 + ty * 8];
      *(float4*)&a[4] = *(const float4*)&As[kk * 132 + ty * 8 + 4];
      *(float4*)&b[0] = *(const float4*)&Bs[kk * 132 + tx * 8];
      *(float4*)&b[4] = *(const float4*)&Bs[kk * 132 + tx * 8 + 4];
      #pragma unroll
      for (int i = 0; i < 8; ++i)
        #pragma unroll
        for (int jj = 0; jj < 8; ++jj)
          acc[i][jj] += a[i] * b[jj];
    }
  }
  float g[8], bb[8];
  #pragma unroll
  for (int jj = 0; jj < 8; ++jj) { g[jj] = gamma[tx * 8 + jj]; bb[jj] = beta[tx * 8 + jj]; }
  #pragma unroll
  for (int i = 0; i < 8; ++i) {
    float s = 0.f, sq = 0.f;
    #pragma unroll
    for (int jj = 0; jj < 8; ++jj) { s += acc[i][jj]; sq += acc[i][jj] * acc[i][jj]; }
    #pragma unroll
    for (int m = 1; m < 16; m <<= 1) {
      s += __shfl_xor(s, m, 64);
      sq += __shfl_xor(sq, m, 64);
    }
    float mean = s * (1.0f / 128.0f);
    float var = sq * (1.0f / 128.0f) - mean * mean;
    float rs = 1.0f / sqrtf(var + 1e-5f);
    float o[8];
    #pragma unroll
    for (int jj = 0; jj < 8; ++jj) o[jj] = (acc[i][jj] - mean) * rs * g[jj] + bb[jj];
    float* dst = &Q[(size_t)(m0 + ty * 8 + i) * DQ + n0 + tx * 8];
    *(float4*)dst = make_float4(o[0], o[1], o[2], o[3]);
    *(float4*)(dst + 4) = make_float4(o[4], o[5], o[6], o[7]);
  }
}

// ---------------- dots GEMM + parallel 16/lane bitonic top-32 (+opt convert) ----------------
#define CE(a, b, dd)                                                           \
  {                                                                            \
    bool sw = (dd) ? rank_before(s[a], id[a], s[b], id[b])                     \
                   : rank_before(s[b], id[b], s[a], id[a]);                    \
    if (sw) {                                                                  \
      float ts = s[a]; s[a] = s[b]; s[b] = ts;                                 \
      int ti = id[a]; id[a] = id[b]; id[b] = ti;                               \
    }                                                                          \
  }
#define CROSSM(M, dd)                                                          \
  {                                                                            \
    bool flip = ((j & (M)) != 0) != (dd);                                      \
    _Pragma("unroll")                                                          \
    for (int r = 0; r < 16; ++r) {                                             \
      float os = __shfl_xor(s[r], (M), 64);                                    \
      int oi = __shfl_xor(id[r], (M), 64);                                     \
      bool take = rank_before(os, oi, s[r], id[r]) != flip;                    \
      if (take) { s[r] = os; id[r] = oi; }                                     \
    }                                                                          \
  }
#define INTRA_L(L, dd)                                                         \
  {                                                                            \
    _Pragma("unroll")                                                          \
    for (int base = 0; base < 16; base += 2 * (L))                             \
      _Pragma("unroll")                                                        \
      for (int o = 0; o < (L); ++o) CE(base + o, base + o + (L), dd);          \
  }
#define INTRA_SET(dd) INTRA_L(8, dd) INTRA_L(4, dd) INTRA_L(2, dd) INTRA_L(1, dd)

__global__ __launch_bounds__(512, 4) void dots_sel(
    const float* __restrict__ Q, const float* __restrict__ keys,
    float* __restrict__ s1s, int* __restrict__ s1i,
    const float* __restrict__ values, unsigned int* __restrict__ vbf) {
  __shared__ float Qs[32 * 132];
  __shared__ float Bs[16 * 260];
  __shared__ float Ts[8 * 1280];  // per-wave transpose region: 4 tok x 320
  if (blockIdx.x >= 1024) {  // fused values->bf16 convert section
    const size_t gbase = ((size_t)(blockIdx.x - 1024) * 512 + threadIdx.x) * 8;
    float4 a = *(const float4*)(values + gbase);
    float4 b = *(const float4*)(values + gbase + 4);
    uint4 pk;
    pk.x = f2bf(a.x) | (f2bf(a.y) << 16);
    pk.y = f2bf(a.z) | (f2bf(a.w) << 16);
    pk.z = f2bf(b.x) | (f2bf(b.y) << 16);
    pk.w = f2bf(b.z) | (f2bf(b.w) << 16);
    *(uint4*)(vbf + gbase / 2) = pk;
    return;
  }
  const int hp = blockIdx.x & 15;
  const int chunk = blockIdx.x >> 4;
  const int h = hp >> 1, p = hp & 1;
  const int t0 = chunk * 32;
  const int tid = threadIdx.x;
  const int w = tid >> 6, lane = tid & 63;
  {
    const int tok = tid >> 4, d0 = (tid & 15) * 8;
    const float* src = &Q[(size_t)(t0 + tok) * DQ + p * 1024 + h * 128 + d0];
    *(float4*)&Qs[tok * 132 + d0] = *(const float4*)src;
    *(float4*)&Qs[tok * 132 + d0 + 4] = *(const float4*)(src + 4);
  }
  const int bn = tid >> 1, bkh = (tid & 1) * 8;
  const float* kbase = keys + ((size_t)(h * NKEYS + bn) * 2 + p) * 128;
  float acc[4][4] = {};
  float4 b0 = *(const float4*)&kbase[bkh];
  float4 b1 = *(const float4*)&kbase[bkh + 4];
  for (int kt = 0; kt < 128; kt += 16) {
    __syncthreads();
    Bs[(bkh + 0) * 260 + bn] = b0.x; Bs[(bkh + 1) * 260 + bn] = b0.y;
    Bs[(bkh + 2) * 260 + bn] = b0.z; Bs[(bkh + 3) * 260 + bn] = b0.w;
    Bs[(bkh + 4) * 260 + bn] = b1.x; Bs[(bkh + 5) * 260 + bn] = b1.y;
    Bs[(bkh + 6) * 260 + bn] = b1.z; Bs[(bkh + 7) * 260 + bn] = b1.w;
    __syncthreads();
    if (kt + 16 < 128) {
      b0 = *(const float4*)&kbase[kt + 16 + bkh];
      b1 = *(const float4*)&kbase[kt + 16 + bkh + 4];
    }
    #pragma unroll
    for (int k4 = 0; k4 < 16; k4 += 4) {
      float4 a0 = *(const float4*)&Qs[(w * 4 + 0) * 132 + kt + k4];
      float4 a1 = *(const float4*)&Qs[(w * 4 + 1) * 132 + kt + k4];
      float4 a2 = *(const float4*)&Qs[(w * 4 + 2) * 132 + kt + k4];
      float4 a3 = *(const float4*)&Qs[(w * 4 + 3) * 132 + kt + k4];
      const float a0r[4] = {a0.x, a0.y, a0.z, a0.w};
      const float a1r[4] = {a1.x, a1.y, a1.z, a1.w};
      const float a2r[4] = {a2.x, a2.y, a2.z, a2.w};
      const float a3r[4] = {a3.x, a3.y, a3.z, a3.w};
      #pragma unroll
      for (int kk = 0; kk < 4; ++kk) {
        float4 b4 = *(const float4*)&Bs[(k4 + kk) * 260 + lane * 4];
        const float br[4] = {b4.x, b4.y, b4.z, b4.w};
        #pragma unroll
        for (int jj = 0; jj < 4; ++jj) {
          acc[0][jj] += a0r[kk] * br[jj];
          acc[1][jj] += a1r[kk] * br[jj];
          acc[2][jj] += a2r[kk] * br[jj];
          acc[3][jj] += a3r[kk] * br[jj];
        }
      }
    }
  }
  // per-wave transpose: (lane: keys 4l..4l+3 x 4 tokens) -> (lane g*16+j: keys 16j..16j+15 of token g)
  // key m of token g stored at g*320 + (m>>4)*20 + (m&15); same-wave DS ordering, no barrier needed
  float* twav = &Ts[w * 1280];
  #pragma unroll
  for (int g2 = 0; g2 < 4; ++g2)
    *(float4*)&twav[g2 * 320 + (lane >> 2) * 20 + (lane & 3) * 4] =
        make_float4(acc[g2][0], acc[g2][1], acc[g2][2], acc[g2][3]);
  const int g = lane >> 4, j = lane & 15;
  float s[16]; int id[16];
  {
    const float* rbase = &twav[g * 320 + j * 20];
    #pragma unroll
    for (int q = 0; q < 4; ++q) {
      float4 v4 = *(const float4*)&rbase[q * 4];
      s[q * 4 + 0] = v4.x; s[q * 4 + 1] = v4.y;
      s[q * 4 + 2] = v4.z; s[q * 4 + 3] = v4.w;
    }
    #pragma unroll
    for (int r = 0; r < 16; ++r) id[r] = j * 16 + r;
  }
  // bitonic sort, 256 elems, e = j*16 + r, descending w/ index tie-break
  // K=2
  #pragma unroll
  for (int base = 0; base < 16; base += 2) CE(base, base + 1, (base & 2) != 0);
  // K=4
  #pragma unroll
  for (int base = 0; base < 16; base += 4) {
    CE(base + 0, base + 2, (base & 4) != 0);
    CE(base + 1, base + 3, (base & 4) != 0);
  }
  #pragma unroll
  for (int base = 0; base < 16; base += 2) CE(base, base + 1, (base & 4) != 0);
  // K=8
  #pragma unroll
  for (int base = 0; base < 16; base += 8)
    #pragma unroll
    for (int o = 0; o < 4; ++o) CE(base + o, base + o + 4, (base & 8) != 0);
  #pragma unroll
  for (int base = 0; base < 16; base += 4) {
    CE(base + 0, base + 2, (base & 8) != 0);
    CE(base + 1, base + 3, (base & 8) != 0);
  }
  #pragma unroll
  for (int base = 0; base < 16; base += 2) CE(base, base + 1, (base & 8) != 0);
  // K=16 (intra only)
  { bool dd = (j & 1) != 0; INTRA_SET(dd) }
  // K=32
  { bool dd = (j & 2) != 0; CROSSM(1, dd) INTRA_SET(dd) }
  // K=64
  { bool dd = (j & 4) != 0; CROSSM(2, dd) CROSSM(1, dd) INTRA_SET(dd) }
  // K=128
  { bool dd = (j & 8) != 0; CROSSM(4, dd) CROSSM(2, dd) CROSSM(1, dd) INTRA_SET(dd) }
  // K=256 (final, descending)
  { CROSSM(8, false) CROSSM(4, false) CROSSM(2, false) CROSSM(1, false) INTRA_SET(false) }
  if (j < 2) {
    const int inst = (t0 + w * 4 + g) * 16 + hp;
    float* so = &s1s[(size_t)inst * KSEL + j * 16];
    int* io = &s1i[(size_t)inst * KSEL + j * 16];
    #pragma unroll
    for (int q = 0; q < 4; ++q) {
      *(float4*)&so[q * 4] = make_float4(s[q * 4], s[q * 4 + 1], s[q * 4 + 2], s[q * 4 + 3]);
      *(int4*)&io[q * 4] = make_int4(id[q * 4], id[q * 4 + 1], id[q * 4 + 2], id[q * 4 + 3]);
    }
  }
}

// ---------------- stage-2: pruned 119-candidate bitonic top-32 (+opt convert) ----------------
__constant__ unsigned short slot_ij[128] = {
  0,1,2,3,4,5,6,7,8,9,10,11,12,13,14,15,16,17,18,19,20,21,22,23,24,25,26,27,28,29,30,31,
  32,33,34,35,36,37,38,39,40,41,42,43,44,45,46,47,
  64,65,66,67,68,69,70,71,72,73,
  96,97,98,99,100,101,102,103,
  128,129,130,131,132,133,
  160,161,162,163,164,
  192,193,194,195,
  224,225,226,227,
  256,257,258,
  288,289,290,
  320,321, 352,353, 384,385, 416,417, 448,449, 480,481,
  512,544,576,608,640,672,704,736,768,800,832,864,896,928,960,992,
  0xFFFF,0xFFFF,0xFFFF,0xFFFF,0xFFFF,0xFFFF,0xFFFF,0xFFFF,0xFFFF
};

__global__ __launch_bounds__(256) void stage2_kernel(
    const float* __restrict__ s1s, const int* __restrict__ s1i,
    float* __restrict__ wgt, int* __restrict__ vidx,
    const float* __restrict__ values, unsigned int* __restrict__ vbf) {
  if (blockIdx.x >= 4096) {  // fused values->bf16 convert section
    const size_t gbase = ((size_t)(blockIdx.x - 4096) * 256 + threadIdx.x) * 8;
    float4 a = *(const float4*)(values + gbase);
    float4 b = *(const float4*)(values + gbase + 4);
    uint4 pk;
    pk.x = f2bf(a.x) | (f2bf(a.y) << 16);
    pk.y = f2bf(a.z) | (f2bf(a.w) << 16);
    pk.z = f2bf(b.x) | (f2bf(b.y) << 16);
    pk.w = f2bf(b.z) | (f2bf(b.w) << 16);
    *(uint4*)(vbf + gbase / 2) = pk;
    return;
  }
  const int th = blockIdx.x * 4 + (threadIdx.x >> 6);
  const int lane = threadIdx.x & 63;
  const int bx = th * 64;
  const int by = bx + 32;
  float s[2]; int id[2];
  #pragma unroll
  for (int r = 0; r < 2; ++r) {
    int sl = slot_ij[lane * 2 + r];
    if (sl != 0xFFFF) {
      s[r] = s1s[bx + (sl >> 5)] + s1s[by + (sl & 31)];
      id[r] = sl;
    } else {
      s[r] = -INFINITY; id[r] = 0x7fffffff;
    }
  }
  #define CE2(dd)                                                              \
    {                                                                          \
      bool sw = (dd) ? rank_before(s[0], id[0], s[1], id[1])                   \
                     : rank_before(s[1], id[1], s[0], id[0]);                  \
      if (sw) {                                                                \
        float ts = s[0]; s[0] = s[1]; s[1] = ts;                               \
        int ti = id[0]; id[0] = id[1]; id[1] = ti;                             \
      }                                                                        \
    }
  #define CROSS2(L, dd)                                                        \
    {                                                                          \
      bool amHigh = (lane & (L)) != 0;                                         \
      bool flip = amHigh != (dd);                                              \
      _Pragma("unroll")                                                        \
      for (int r = 0; r < 2; ++r) {                                            \
        float os = __shfl_xor(s[r], (L), 64);                                  \
        int oi = __shfl_xor(id[r], (L), 64);                                   \
        bool take = rank_before(os, oi, s[r], id[r]) != flip;                  \
        if (take) { s[r] = os; id[r] = oi; }                                   \
      }                                                                        \
    }
  { bool dd = (lane & 1) != 0; CE2(dd); }
  #pragma unroll
  for (int K = 4; K <= 128; K <<= 1) {
    bool dd = (lane & (K >> 1)) != 0;
    #pragma unroll
    for (int L = K >> 2; L >= 1; L >>= 1) CROSS2(L, dd);
    CE2(dd);
  }
  #undef CE2
  #undef CROSS2
  float smax = __shfl(s[0], 0, 64);
  float e0 = 0.f, e1 = 0.f;
  if (lane < 16) { e0 = expf(s[0] - smax); e1 = expf(s[1] - smax); }
  float part = e0 + e1;
  #pragma unroll
  for (int m = 1; m < 16; m <<= 1) part += __shfl_xor(part, m, 64);
  if (lane < 16) {
    int f0 = id[0], f1 = id[1];
    int vi0 = s1i[bx + (f0 >> 5)] * NKEYS + s1i[by + (f0 & 31)];
    int vi1 = s1i[bx + (f1 >> 5)] * NKEYS + s1i[by + (f1 & 31)];
    wgt[(size_t)th * KSEL + lane * 2] = e0 / part;
    wgt[(size_t)th * KSEL + lane * 2 + 1] = e1 / part;
    vidx[(size_t)th * KSEL + lane * 2] = vi0;
    vidx[(size_t)th * KSEL + lane * 2 + 1] = vi1;
  }
}

// ---------------- gather bf16: wave-per-row, 4 L3 phases ----------------
__global__ __launch_bounds__(256) void gather_bf16(
    const float* __restrict__ wgt, const int* __restrict__ vidx,
    const unsigned short* __restrict__ vbf, float* __restrict__ out) {
  const int t = blockIdx.x;
  const int tid = threadIdx.x, w = tid >> 6, lane = tid & 63;
  __shared__ float ws_[256];
  __shared__ int vs_[256];
  __shared__ float part[4 * 520];
  ws_[tid] = wgt[(size_t)t * 256 + tid];
  vs_[tid] = vidx[(size_t)t * 256 + tid];
  __syncthreads();
  float acc[8] = {};
  const int c0 = lane * 8;
  #pragma unroll 1
  for (int phase = 0; phase < 4; ++phase) {
    for (int e = w; e < 256; e += 4) {
      const int row = vs_[e];
      if ((row >> 14) != phase) continue;
      const float wv = ws_[e];
      uint4 pk = *(const uint4*)(vbf + (size_t)row * CDIM + c0);
      acc[0] += wv * bf2f(pk.x & 0xffff); acc[1] += wv * bf2f(pk.x >> 16);
      acc[2] += wv * bf2f(pk.y & 0xffff); acc[3] += wv * bf2f(pk.y >> 16);
      acc[4] += wv * bf2f(pk.z & 0xffff); acc[5] += wv * bf2f(pk.z >> 16);
      acc[6] += wv * bf2f(pk.w & 0xffff); acc[7] += wv * bf2f(pk.w >> 16);
    }
  }
  #pragma unroll
  for (int jj = 0; jj < 8; jj += 4)
    *(float4*)&part[w * 520 + c0 + jj] =
        make_float4(acc[jj], acc[jj + 1], acc[jj + 2], acc[jj + 3]);
  __syncthreads();
  const int c2 = tid * 2;
  float r0 = part[c2] + part[520 + c2] + part[1040 + c2] + part[1560 + c2];
  float r1 = part[c2 + 1] + part[520 + c2 + 1] + part[1040 + c2 + 1] + part[1560 + c2 + 1];
  *(float2*)(out + (size_t)t * CDIM + c2) = make_float2(r0, r1);
}

// ---------------- fallback fp32 gather ----------------
__global__ __launch_bounds__(256) void gather_kernel(
    const float* __restrict__ wgt, const int* __restrict__ vidx,
    const float* __restrict__ values, float* __restrict__ out) {
  const int tp = blockIdx.x;
  const int tid = threadIdx.x;
  __shared__ float ws_[512];
  __shared__ int vs_[512];
  ws_[tid] = wgt[(size_t)tp * 512 + tid];
  ws_[tid + 256] = wgt[(size_t)tp * 512 + tid + 256];
  vs_[tid] = vidx[(size_t)tp * 512 + tid];
  vs_[tid + 256] = vidx[(size_t)tp * 512 + tid + 256];
  __syncthreads();
  const int sub = tid >> 7;
  const int c4 = (tid & 127) * 4;
  const float* wp = &ws_[sub * 256];
  const int* vp = &vs_[sub * 256];
  float4 a = make_float4(0.f, 0.f, 0.f, 0.f);
  #pragma unroll 4
  for (int e = 0; e < 256; ++e) {
    float4 vv = *(const float4*)(values + (size_t)vp[e] * CDIM + c4);
    float wv = wp[e];
    a.x += wv * vv.x; a.y += wv * vv.y; a.z += wv * vv.z; a.w += wv * vv.w;
  }
  *(float4*)(out + (size_t)(tp * 2 + sub) * CDIM + c4) = a;
}

extern "C" void kernel_launch(void* const* d_in, const int* in_sizes, int n_in,
                              void* d_out, int out_size, void* d_ws, size_t ws_size,
                              hipStream_t stream) {
  const float* X      = (const float*)d_in[0];
  const float* W      = (const float*)d_in[1];
  const float* keys   = (const float*)d_in[2];
  const float* values = (const float*)d_in[3];
  const float* gamma  = (const float*)d_in[4];
  const float* beta   = (const float*)d_in[5];
  char* ws = (char*)d_ws;
  float* s1s = (float*)(ws);                  // 0..4 MB
  int*   s1i = (int*)  (ws + (4u << 20));     // 4..8 MB
  float* wgt = (float*)(ws + (8u << 20));     // 8..10 MB
  int*   vix = (int*)  (ws + (10u << 20));    // 10..12 MB
  float* Q   = (float*)(ws + (12u << 20));    // 12..28 MB (dead after dots_sel)
  unsigned int* vbf_hi = (unsigned int*)(ws + (28u << 20));  // 28..92 MB (no overlap)
  unsigned int* vbf_lo = (unsigned int*)(ws + (12u << 20));  // 12..76 MB (overlays dead Q)

  const bool fuse_dots  = ws_size >= (92u << 20);
  const bool bf16_path  = ws_size >= (76u << 20);
  unsigned int* vbf = fuse_dots ? vbf_hi : vbf_lo;

  qgemm_ln<<<dim3(16, 16), 256, 0, stream>>>(X, W, gamma, beta, Q);
  dots_sel<<<fuse_dots ? 9216 : 1024, 512, 0, stream>>>(Q, keys, s1s, s1i, values, vbf);
  stage2_kernel<<<(bf16_path && !fuse_dots) ? 20480 : 4096, 256, 0, stream>>>(
      s1s, s1i, wgt, vix, values, vbf);
  if (bf16_path) {
    gather_bf16<<<2048, 256, 0, stream>>>(wgt, vix, (const unsigned short*)vbf, (float*)d_out);
  } else {
    gather_kernel<<<1024, 256, 0, stream>>>(wgt, vix, values, (float*)d_out);
  }
}